// Round 1
// baseline (237.965 us; speedup 1.0000x reference)
//
#include <hip/hip_runtime.h>

// VQ-VAE forward via bf16 MFMA distance scan.
//   score(token,code) = dot(x,w) - ||w||^2/2   (maximize == argmin distance)
//   dist_best = -2*score_best;  SSE = sum(xsq) + sum(dist_best)
//
// R4: occupancy 2x — TOKB 256->128 (32 tokens/wave, 2 tile-chains), grid 1024
//     = 4 blocks/CU (was 2). vq_final fused into vq_main via last-block ticket.
//     vq_init widened to 16 blocks.
//
// ws layout: [0,4096) u32 counts[1024] | [4096,4104) double sse
//            [5120,5124) u32 ticket
//            [8192,12288) float wnh[1024] (= -0.5||w||^2)
//            [16384,16384+131072) bf16 W_bf[1024][64]

typedef __bf16          bf16x8  __attribute__((ext_vector_type(8)));
typedef float           f32x4   __attribute__((ext_vector_type(4)));
typedef unsigned short  ushortx8 __attribute__((ext_vector_type(8)));

constexpr int D = 64;
constexpr int K = 1024;
constexpr int CHUNK = 256;            // codes staged in LDS per pass
constexpr int TOKB = 128;             // tokens per block (32/wave x 4 waves)

__device__ __forceinline__ unsigned short f2bf(float f) {
  unsigned u = __builtin_bit_cast(unsigned, f);
  u = (u + 0x7fffu + ((u >> 16) & 1u)) >> 16;  // RNE
  return (unsigned short)u;
}

__global__ __launch_bounds__(64) void vq_init(const float* __restrict__ W,
                                              unsigned* __restrict__ counts,
                                              float* __restrict__ wnh,
                                              double* __restrict__ sse,
                                              unsigned* __restrict__ ticket,
                                              ushortx8* __restrict__ wbf) {
  const int c = blockIdx.x * 64 + threadIdx.x;  // 0..1023
  const float4* row = reinterpret_cast<const float4*>(W + c * D);
  float s = 0.f;
#pragma unroll
  for (int j = 0; j < 8; ++j) {
    float4 v0 = row[2 * j], v1 = row[2 * j + 1];
    s = fmaf(v0.x, v0.x, s); s = fmaf(v0.y, v0.y, s);
    s = fmaf(v0.z, v0.z, s); s = fmaf(v0.w, v0.w, s);
    s = fmaf(v1.x, v1.x, s); s = fmaf(v1.y, v1.y, s);
    s = fmaf(v1.z, v1.z, s); s = fmaf(v1.w, v1.w, s);
    ushortx8 p;
    p[0] = f2bf(v0.x); p[1] = f2bf(v0.y); p[2] = f2bf(v0.z); p[3] = f2bf(v0.w);
    p[4] = f2bf(v1.x); p[5] = f2bf(v1.y); p[6] = f2bf(v1.z); p[7] = f2bf(v1.w);
    wbf[c * 8 + j] = p;
  }
  wnh[c] = -0.5f * s;
  counts[c] = 0u;
  if (c == 0) { *sse = 0.0; *ticket = 0u; }
}

// 256 threads = 4 waves; 32 tokens/wave (2 A-tiles of 16) -> 128 tokens/block.
__global__ __launch_bounds__(256, 4) void vq_main(const float* __restrict__ x,
                                                  const float* __restrict__ Wf,
                                                  const uint4* __restrict__ wbf,
                                                  const float* __restrict__ wnh,
                                                  unsigned* __restrict__ counts,
                                                  double* __restrict__ sse,
                                                  unsigned* __restrict__ ticket,
                                                  float* __restrict__ out,
                                                  int n_tokens) {
  // Swizzled B: for each 16-code tile ct, slot layout is exactly the lane
  // order of the two wave reads: b0 at [ct*128 + lane], b1 at [ct*128+64+lane].
  __shared__ uint4 s_w[CHUNK * 8];     // 32 KB
  __shared__ float s_wnh[CHUNK];       // 1 KB
  __shared__ unsigned s_hist[K];       // 4 KB
  __shared__ unsigned s_idx[TOKB];     // 0.5 KB
  __shared__ float s_red[4];
  __shared__ unsigned s_ured[4];
  __shared__ unsigned s_last;

  const int tid = threadIdx.x;
  const int wv = tid >> 6, lane = tid & 63;
  const int g = lane >> 4, nl = lane & 15;
  const int tokwg = blockIdx.x * TOKB;

  for (int i = tid; i < K; i += 256) s_hist[i] = 0u;

  // A fragments: lane holds A[m=lane&15][k=(lane>>4)*8+j]; 2 token tiles.
  bf16x8 afrag[2][2];
  float xsq = 0.f;
#pragma unroll
  for (int tt = 0; tt < 2; ++tt) {
#pragma unroll
    for (int s = 0; s < 2; ++s) {
      const float* px = x + (size_t)(tokwg + wv * 32 + tt * 16 + nl) * D + s * 32 + g * 8;
      float4 v0 = *reinterpret_cast<const float4*>(px);
      float4 v1 = *reinterpret_cast<const float4*>(px + 4);
      xsq = fmaf(v0.x, v0.x, xsq); xsq = fmaf(v0.y, v0.y, xsq);
      xsq = fmaf(v0.z, v0.z, xsq); xsq = fmaf(v0.w, v0.w, xsq);
      xsq = fmaf(v1.x, v1.x, xsq); xsq = fmaf(v1.y, v1.y, xsq);
      xsq = fmaf(v1.z, v1.z, xsq); xsq = fmaf(v1.w, v1.w, xsq);
      ushortx8 p;
      p[0] = f2bf(v0.x); p[1] = f2bf(v0.y); p[2] = f2bf(v0.z); p[3] = f2bf(v0.w);
      p[4] = f2bf(v1.x); p[5] = f2bf(v1.y); p[6] = f2bf(v1.z); p[7] = f2bf(v1.w);
      afrag[tt][s] = __builtin_bit_cast(bf16x8, p);
    }
  }

  float best[2][4];
  unsigned bidx[2][4];
#pragma unroll
  for (int tt = 0; tt < 2; ++tt)
#pragma unroll
    for (int j = 0; j < 4; ++j) { best[tt][j] = -3.0e38f; bidx[tt][j] = 0u; }

  for (int cb = 0; cb < K; cb += CHUNK) {
    __syncthreads();
    // Stage 256 codes, swizzled into wave-read order. Global reads are
    // perfectly coalesced (slot index == linear); LDS writes balanced
    // (one lane per bank-quad per phase).
    for (int i = tid; i < CHUNK * 8; i += 256) {
      const int code = i >> 3, part = i & 7;
      const int ct = code >> 4, cnl = code & 15;
      const int half = part >> 2, q = part & 3;
      s_w[ct * 128 + half * 64 + q * 16 + cnl] = wbf[(size_t)(cb + code) * 8 + part];
    }
    s_wnh[tid] = wnh[cb + tid];
    __syncthreads();

#pragma unroll
    for (int ct = 0; ct < CHUNK / 16; ++ct) {
      const float w0 = s_wnh[ct * 16 + nl];
      bf16x8 b0 = __builtin_bit_cast(bf16x8, s_w[ct * 128 + lane]);        // conflict-free
      bf16x8 b1 = __builtin_bit_cast(bf16x8, s_w[ct * 128 + 64 + lane]);   // conflict-free
      const unsigned code0 = (unsigned)(cb + ct * 16 + nl);
      f32x4 acc[2];
#pragma unroll
      for (int tt = 0; tt < 2; ++tt) {
        acc[tt] = (f32x4){w0, w0, w0, w0};  // C init = -||w||^2/2 (per col)
        acc[tt] = __builtin_amdgcn_mfma_f32_16x16x32_bf16(afrag[tt][0], b0, acc[tt], 0, 0, 0);
        acc[tt] = __builtin_amdgcn_mfma_f32_16x16x32_bf16(afrag[tt][1], b1, acc[tt], 0, 0, 0);
      }
#pragma unroll
      for (int tt = 0; tt < 2; ++tt)
#pragma unroll
        for (int j = 0; j < 4; ++j) {
          if (acc[tt][j] > best[tt][j]) { best[tt][j] = acc[tt][j]; bidx[tt][j] = code0; }
        }
    }
  }

  // Cross-lane argmax over the 16 cols; C/D row = 4*g+j, col = nl.
  float ddist = 0.f;
#pragma unroll
  for (int tt = 0; tt < 2; ++tt) {
#pragma unroll
    for (int j = 0; j < 4; ++j) {
      float b = best[tt][j];
      unsigned bi = bidx[tt][j];
#pragma unroll
      for (int off = 1; off < 16; off <<= 1) {
        float ob = __shfl_xor(b, off, 64);
        unsigned oi = __shfl_xor(bi, off, 64);
        if (ob > b || (ob == b && oi < bi)) { b = ob; bi = oi; }
      }
      if (nl == 0) {
        int tl = wv * 32 + tt * 16 + 4 * g + j;
        s_idx[tl] = bi;
        atomicAdd(&s_hist[bi], 1u);
        ddist = fmaf(-2.0f, b, ddist);  // dist = wsq - 2*dot >= 0
      }
    }
  }

  // Block-reduce SSE contribution: sum(x^2) + sum(dist_best).
  float sv = xsq + ddist;
#pragma unroll
  for (int off = 32; off > 0; off >>= 1) sv += __shfl_down(sv, off, 64);
  if (lane == 0) s_red[wv] = sv;
  __syncthreads();  // also publishes s_idx / orders s_hist atomics
  if (tid == 0) atomicAdd(sse, (double)((s_red[0] + s_red[1]) + (s_red[2] + s_red[3])));

  for (int i = tid; i < K; i += 256) {
    unsigned h = s_hist[i];
    if (h) atomicAdd(&counts[i], h);
  }

  // out = W[idx] (fp32 gather; == x + (q - x) to <=1 ulp).
  const int d4 = tid & 15;
#pragma unroll
  for (int tk = 0; tk < 8; ++tk) {
    int tl = tk * 16 + (tid >> 4);
    unsigned ci = s_idx[tl];
    float4 q = *reinterpret_cast<const float4*>(Wf + ci * D + d4 * 4);
    *reinterpret_cast<float4*>(out + (size_t)(tokwg + tl) * D + d4 * 4) = q;
  }

  // ---- fused final: last block to finish does the tail reduction ----
  __threadfence();           // make this thread's counts/sse updates visible
  __syncthreads();
  if (tid == 0) {
    unsigned t = atomicAdd(ticket, 1u);
    s_last = (t == gridDim.x - 1) ? 1u : 0u;
  }
  __syncthreads();
  if (s_last) {
    __threadfence();
    const float inv_n = 1.0f / (float)n_tokens;
    float s = 0.f;
    unsigned u = 0;
    for (int c = tid; c < K; c += 256) {
      unsigned cnt = atomicAdd(&counts[c], 0u);  // coherent RMW read
      float p = (float)cnt * inv_n;
      s += p * logf(p + 1e-10f);
      u += (cnt >= 1u) ? 1u : 0u;
    }
#pragma unroll
    for (int off = 32; off > 0; off >>= 1) {
      s += __shfl_down(s, off, 64);
      u += __shfl_down(u, off, 64);
    }
    if (lane == 0) { s_red[wv] = s; s_ured[wv] = u; }
    __syncthreads();
    if (tid == 0) {
      double sv2 = atomicAdd(sse, 0.0);  // coherent read of final SSE
      float s2 = (s_red[0] + s_red[1]) + (s_red[2] + s_red[3]);
      unsigned u2 = s_ured[0] + s_ured[1] + s_ured[2] + s_ured[3];
      double mean = sv2 / ((double)n_tokens * (double)D);
      float* out_tail = out + (size_t)n_tokens * D;
      out_tail[0] = 3.0f * (float)mean;  // q_latent + 2*e_latent
      out_tail[1] = expf(-s2);           // perplexity
      out_tail[2] = (float)u2;           // usage
    }
  }
}

extern "C" void kernel_launch(void* const* d_in, const int* in_sizes, int n_in,
                              void* d_out, int out_size, void* d_ws, size_t ws_size,
                              hipStream_t stream) {
  const float* x = (const float*)d_in[0];
  const float* W = (const float*)d_in[1];
  float* out = (float*)d_out;

  unsigned* counts = (unsigned*)d_ws;
  double* sse = (double*)((char*)d_ws + 4096);
  unsigned* ticket = (unsigned*)((char*)d_ws + 5120);
  float* wnh = (float*)((char*)d_ws + 8192);
  void* wbf = (void*)((char*)d_ws + 16384);

  const int n_tokens = in_sizes[0] / D;  // 131072
  const int blocks = n_tokens / TOKB;    // 1024

  vq_init<<<K / 64, 64, 0, stream>>>(W, counts, wnh, sse, ticket, (ushortx8*)wbf);
  vq_main<<<blocks, 256, 0, stream>>>(x, W, (const uint4*)wbf, wnh, counts, sse, ticket,
                                      out, n_tokens);
}